// Round 1
// baseline (915.514 us; speedup 1.0000x reference)
//
#include <hip/hip_runtime.h>
#include <hip/hip_bf16.h>
#include <cstdint>
#include <cstddef>

#define DIM 1024
#define B_SZ 32
#define L_SZ 2048

#define BM 128
#define BN 128
#define BK 32
#define LDS_STRIDE 40   // 32 + 8 bf16 pad: breaks power-of-2 bank stride, keeps 16B alignment

typedef __attribute__((ext_vector_type(8))) short bf16x8;
typedef __attribute__((ext_vector_type(4))) float floatx4;

static __device__ __forceinline__ unsigned cvt2_bf16_rne(float a, float b) {
    unsigned ua = __builtin_bit_cast(unsigned, a);
    unsigned ub = __builtin_bit_cast(unsigned, b);
    ua = (ua + 0x7FFFu + ((ua >> 16) & 1u)) >> 16;
    ub = (ub + 0x7FFFu + ((ub >> 16) & 1u)) >> 16;
    return ua | (ub << 16);
}

// tanh(x) = 1 - 2/(e^{2x}+1); exact at +-inf limits, ~1e-6 rel error (v_exp + v_rcp)
static __device__ __forceinline__ float tanh_fast(float x) {
    float e = __expf(2.0f * x);
    return 1.0f - 2.0f * __builtin_amdgcn_rcpf(e + 1.0f);
}

// ---------------------------------------------------------------------------
// ht_proj[b][k] = sum_d x[b][d] * Wa[k][d]   (first half of Wa columns)
// grid (32, 16), block 256 = 4 waves; each wave reduces 16 k-rows.
// ---------------------------------------------------------------------------
__global__ __launch_bounds__(256) void ht_kernel(const float* __restrict__ x,
                                                 const float* __restrict__ Wa,
                                                 float* __restrict__ ht) {
    const int b = blockIdx.x, kb = blockIdx.y, t = threadIdx.x;
    __shared__ float xs[DIM];
    for (int i = t; i < DIM; i += 256) xs[i] = x[b * DIM + i];
    __syncthreads();
    const int wave = t >> 6, lane = t & 63;
    for (int kk = 0; kk < 16; ++kk) {
        const int k = kb * 64 + wave * 16 + kk;
        const float* wr = Wa + (size_t)k * (2 * DIM);   // row k, first DIM cols
        float s = 0.f;
        #pragma unroll
        for (int d = 0; d < DIM; d += 64) s += xs[d + lane] * wr[d + lane];
        #pragma unroll
        for (int off = 32; off > 0; off >>= 1) s += __shfl_xor(s, off);
        if (lane == 0) ht[b * DIM + k] = s;
    }
}

// ---------------------------------------------------------------------------
// Fused GEMM + tanh + Va-reduce:
//   scores[m] += sum_{n in tile} tanh(ctx[m,:]*Wa_s[n,:] + ht[b,n]) * Va[n]
// NT GEMM, bf16 MFMA 16x16x32, 128x128 tile, BK=32, 4 waves (2x2), 4x4 frags.
// grid (8 n-tiles, 512 m-tiles): n-tile -> fixed XCD -> Wa slice L2-resident.
// ---------------------------------------------------------------------------
__global__ __launch_bounds__(256, 2) void gemm_score_kernel(
    const float* __restrict__ ctx, const float* __restrict__ Wa,
    const float* __restrict__ Va, const float* __restrict__ ht,
    float* __restrict__ scores)
{
    __shared__ unsigned short As[BM * LDS_STRIDE];
    __shared__ unsigned short Bs[BN * LDS_STRIDE];
    const int t = threadIdx.x;
    const int n0 = blockIdx.x * BN;
    const int m0 = blockIdx.y * BM;
    const int lane = t & 63, wave = t >> 6;
    const int l15 = lane & 15, quad = lane >> 4;
    const int wm = (wave >> 1) * 64, wn = (wave & 1) * 64;

    // staging map: 256 threads cover 128 rows x 32 cols (fp32) in 4 passes
    const int srow = t >> 3;        // 0..31
    const int scol = (t & 7) * 4;   // 0,4,...,28
    const float* aBase = ctx + (size_t)(m0 + srow) * DIM + scol;
    const float* bBase = Wa + (size_t)(n0 + srow) * (2 * DIM) + DIM + scol;

    floatx4 acc[4][4];
    #pragma unroll
    for (int i = 0; i < 4; ++i)
        #pragma unroll
        for (int j = 0; j < 4; ++j) acc[i][j] = (floatx4)0.f;

    for (int k0 = 0; k0 < DIM; k0 += BK) {
        __syncthreads();
        #pragma unroll
        for (int r = 0; r < 4; ++r) {
            const float4 va = *(const float4*)(aBase + (size_t)(r * 32) * DIM + k0);
            const float4 vb = *(const float4*)(bBase + (size_t)(r * 32) * (2 * DIM) + k0);
            const unsigned pa0 = cvt2_bf16_rne(va.x, va.y), pa1 = cvt2_bf16_rne(va.z, va.w);
            const unsigned pb0 = cvt2_bf16_rne(vb.x, vb.y), pb1 = cvt2_bf16_rne(vb.z, vb.w);
            *(uint2*)&As[(srow + r * 32) * LDS_STRIDE + scol] = make_uint2(pa0, pa1);
            *(uint2*)&Bs[(srow + r * 32) * LDS_STRIDE + scol] = make_uint2(pb0, pb1);
        }
        __syncthreads();
        bf16x8 af[4], bfr[4];
        #pragma unroll
        for (int i = 0; i < 4; ++i)
            af[i] = *(const bf16x8*)&As[(wm + i * 16 + l15) * LDS_STRIDE + quad * 8];
        #pragma unroll
        for (int j = 0; j < 4; ++j)
            bfr[j] = *(const bf16x8*)&Bs[(wn + j * 16 + l15) * LDS_STRIDE + quad * 8];
        #pragma unroll
        for (int i = 0; i < 4; ++i)
            #pragma unroll
            for (int j = 0; j < 4; ++j)
                acc[i][j] = __builtin_amdgcn_mfma_f32_16x16x32_bf16(af[i], bfr[j], acc[i][j], 0, 0, 0);
    }

    // epilogue: hidden = tanh(acc + ht), partial score = sum_n hidden*Va[n]
    // C/D layout: n = lane&15, m = quad*4 + reg   [m89-verified]
    const int bb = m0 >> 11;   // m-tile never straddles a batch row (2048 % 128 == 0)
    float htv[4], vav[4];
    #pragma unroll
    for (int j = 0; j < 4; ++j) {
        const int ng = n0 + wn + j * 16 + l15;
        htv[j] = ht[bb * DIM + ng];
        vav[j] = Va[ng];
    }
    #pragma unroll
    for (int i = 0; i < 4; ++i) {
        #pragma unroll
        for (int r = 0; r < 4; ++r) {
            float s = 0.f;
            #pragma unroll
            for (int j = 0; j < 4; ++j) {
                const float h = tanh_fast(acc[i][j][r] + htv[j]);
                s += h * vav[j];
            }
            // reduce across the 16 lanes (l15) holding different n for this m
            s += __shfl_xor(s, 8);
            s += __shfl_xor(s, 4);
            s += __shfl_xor(s, 2);
            s += __shfl_xor(s, 1);
            if (l15 == 0)
                atomicAdd(&scores[m0 + wm + i * 16 + quad * 4 + r], s);
        }
    }
}

// ---------------------------------------------------------------------------
// softmax over L per batch row; writes attn (also an output)
// ---------------------------------------------------------------------------
__global__ __launch_bounds__(256) void softmax_kernel(const float* __restrict__ scores,
                                                      float* __restrict__ attn) {
    const int b = blockIdx.x, t = threadIdx.x;
    const float* sc = scores + b * L_SZ;
    float* at = attn + b * L_SZ;
    __shared__ float red[256];
    float m = -1e30f;
    for (int l = t; l < L_SZ; l += 256) m = fmaxf(m, sc[l]);
    red[t] = m; __syncthreads();
    for (int s = 128; s > 0; s >>= 1) { if (t < s) red[t] = fmaxf(red[t], red[t + s]); __syncthreads(); }
    m = red[0]; __syncthreads();
    float sum = 0.f;
    for (int l = t; l < L_SZ; l += 256) sum += __expf(sc[l] - m);
    red[t] = sum; __syncthreads();
    for (int s = 128; s > 0; s >>= 1) { if (t < s) red[t] += red[t + s]; __syncthreads(); }
    const float inv = 1.0f / red[0];
    for (int l = t; l < L_SZ; l += 256) at[l] = __expf(sc[l] - m) * inv;
}

// ---------------------------------------------------------------------------
// weighted[b][d] = sum_l attn[b][l] * ctx[b][l][d]
// grid (32, 16): each block does a 128-long l-slice over all D via float4.
// ---------------------------------------------------------------------------
__global__ __launch_bounds__(256) void weighted_kernel(const float* __restrict__ ctx,
                                                       const float* __restrict__ attn,
                                                       float* __restrict__ weighted) {
    const int b = blockIdx.x, slice = blockIdx.y, t = threadIdx.x;
    const float* cb = ctx + ((size_t)b * L_SZ + (size_t)slice * 128) * DIM;
    const float* at = attn + b * L_SZ + slice * 128;
    float4 w = make_float4(0.f, 0.f, 0.f, 0.f);
    for (int l = 0; l < 128; ++l) {
        const float a = at[l];
        const float4 c = *(const float4*)(cb + (size_t)l * DIM + t * 4);
        w.x += a * c.x; w.y += a * c.y; w.z += a * c.z; w.w += a * c.w;
    }
    float* o = weighted + b * DIM + t * 4;
    atomicAdd(o + 0, w.x);
    atomicAdd(o + 1, w.y);
    atomicAdd(o + 2, w.z);
    atomicAdd(o + 3, w.w);
}

extern "C" void kernel_launch(void* const* d_in, const int* in_sizes, int n_in,
                              void* d_out, int out_size, void* d_ws, size_t ws_size,
                              hipStream_t stream) {
    const float* x   = (const float*)d_in[0];   // 32 x 1024
    const float* ctx = (const float*)d_in[1];   // 32 x 2048 x 1024
    const float* Wa  = (const float*)d_in[2];   // 1024 x 2048
    const float* Va  = (const float*)d_in[3];   // 1 x 1024

    float* out      = (float*)d_out;
    float* weighted = out;                      // 32*1024
    float* attn     = out + B_SZ * DIM;         // 32*2048

    float* scores = (float*)d_ws;               // 32*2048 fp32
    float* ht     = scores + B_SZ * L_SZ;       // 32*1024 fp32  (ws needs 384 KB)

    hipMemsetAsync(scores, 0, (size_t)B_SZ * L_SZ * sizeof(float), stream);
    hipMemsetAsync(weighted, 0, (size_t)B_SZ * DIM * sizeof(float), stream);

    ht_kernel<<<dim3(B_SZ, 16), 256, 0, stream>>>(x, Wa, ht);
    gemm_score_kernel<<<dim3(DIM / BN, (B_SZ * L_SZ) / BM), 256, 0, stream>>>(ctx, Wa, Va, ht, scores);
    softmax_kernel<<<B_SZ, 256, 0, stream>>>(scores, attn);
    weighted_kernel<<<dim3(B_SZ, 16), 256, 0, stream>>>(ctx, attn, weighted);
}

// Round 2
// 616.163 us; speedup vs baseline: 1.4858x; 1.4858x over previous
//
#include <hip/hip_runtime.h>
#include <hip/hip_bf16.h>
#include <cstdint>
#include <cstddef>

#define DIM 1024
#define B_SZ 32
#define L_SZ 2048

#define BM 128
#define BN 128

typedef __attribute__((ext_vector_type(8))) short bf16x8;
typedef __attribute__((ext_vector_type(4))) float floatx4;

static __device__ __forceinline__ unsigned cvt2_bf16_rne(float a, float b) {
    unsigned ua = __builtin_bit_cast(unsigned, a);
    unsigned ub = __builtin_bit_cast(unsigned, b);
    ua = (ua + 0x7FFFu + ((ua >> 16) & 1u)) >> 16;
    ub = (ub + 0x7FFFu + ((ub >> 16) & 1u)) >> 16;
    return ua | (ub << 16);
}

static __device__ __forceinline__ float bf2f(unsigned short u) {
    return __builtin_bit_cast(float, (unsigned)u << 16);
}

// tanh(x) = 1 - 2/(e^{2x}+1)
static __device__ __forceinline__ float tanh_fast(float x) {
    float e = __expf(2.0f * x);
    return 1.0f - 2.0f * __builtin_amdgcn_rcpf(e + 1.0f);
}

// async global->LDS, 16B per lane; LDS dest = uniform base + lane*16
static __device__ __forceinline__ void gld_lds16(const void* g, void* lds) {
    __builtin_amdgcn_global_load_lds(
        (const __attribute__((address_space(1))) unsigned int*)g,
        (__attribute__((address_space(3))) unsigned int*)lds,
        16, 0, 0);
}

// ---------------------------------------------------------------------------
// fp32 -> bf16 (RNE) bulk convert: each thread handles 8 floats -> 16B store
// ---------------------------------------------------------------------------
__global__ __launch_bounds__(256) void cvt_ctx_kernel(const float* __restrict__ src,
                                                      unsigned short* __restrict__ dst,
                                                      long n8) {
    long i = (long)blockIdx.x * 256 + threadIdx.x;
    const long stride = (long)gridDim.x * 256;
    for (; i < n8; i += stride) {
        const float4 a = ((const float4*)src)[i * 2];
        const float4 b = ((const float4*)src)[i * 2 + 1];
        uint4 o;
        o.x = cvt2_bf16_rne(a.x, a.y);
        o.y = cvt2_bf16_rne(a.z, a.w);
        o.z = cvt2_bf16_rne(b.x, b.y);
        o.w = cvt2_bf16_rne(b.z, b.w);
        ((uint4*)dst)[i] = o;
    }
}

// Wa_s[k][d] = Wa[k][1024+d] -> packed bf16 [1024][1024]
__global__ __launch_bounds__(256) void cvt_wa_kernel(const float* __restrict__ Wa,
                                                     unsigned short* __restrict__ dst) {
    const int i = blockIdx.x * 256 + threadIdx.x;   // chunk of 8, 131072 total
    const int k = i >> 7, dc = i & 127;
    const float* s = Wa + (size_t)k * (2 * DIM) + DIM + dc * 8;
    const float4 a = ((const float4*)s)[0];
    const float4 b = ((const float4*)s)[1];
    uint4 o;
    o.x = cvt2_bf16_rne(a.x, a.y);
    o.y = cvt2_bf16_rne(a.z, a.w);
    o.z = cvt2_bf16_rne(b.x, b.y);
    o.w = cvt2_bf16_rne(b.z, b.w);
    ((uint4*)(dst + (size_t)k * DIM + dc * 8))[0] = o;
}

// ---------------------------------------------------------------------------
// ht_proj[b][k] = sum_d x[b][d] * Wa[k][d]
// ---------------------------------------------------------------------------
__global__ __launch_bounds__(256) void ht_kernel(const float* __restrict__ x,
                                                 const float* __restrict__ Wa,
                                                 float* __restrict__ ht) {
    const int b = blockIdx.x, kb = blockIdx.y, t = threadIdx.x;
    __shared__ float xs[DIM];
    for (int i = t; i < DIM; i += 256) xs[i] = x[b * DIM + i];
    __syncthreads();
    const int wave = t >> 6, lane = t & 63;
    for (int kk = 0; kk < 16; ++kk) {
        const int k = kb * 64 + wave * 16 + kk;
        const float* wr = Wa + (size_t)k * (2 * DIM);
        float s = 0.f;
        #pragma unroll
        for (int d = 0; d < DIM; d += 64) s += xs[d + lane] * wr[d + lane];
        #pragma unroll
        for (int off = 32; off > 0; off >>= 1) s += __shfl_xor(s, off);
        if (lane == 0) ht[b * DIM + k] = s;
    }
}

// ---------------------------------------------------------------------------
// m97-style bf16 GEMM + fused tanh/Va epilogue.
// A = ctx_bf16 [65536][1024], B = Wa_s_bf16 [1024][1024], NT, BK=64.
// LDS: rows of 64 bf16 (128B), 16B chunks XOR-swizzled by (row&7) so the
// fragment ds_read_b128 is 2-way-conflict max (free). Swizzle is applied on
// the GLOBAL source address (global_load_lds dest is fixed lane*16).
// ---------------------------------------------------------------------------
__global__ __launch_bounds__(256) void gemm_score_bf16(
    const unsigned short* __restrict__ A, const unsigned short* __restrict__ Bm,
    const float* __restrict__ Va, const float* __restrict__ ht,
    float* __restrict__ scores)
{
    __shared__ __align__(16) unsigned short As[BM * 64];
    __shared__ __align__(16) unsigned short Bs[BN * 64];
    const int t = threadIdx.x;
    const int n0 = blockIdx.x * BN;
    const int m0 = blockIdx.y * BM;
    const int lane = t & 63, wave = t >> 6;
    const int l15 = lane & 15, quad = lane >> 4;
    const int wm = (wave >> 1) * 64, wn = (wave & 1) * 64;

    // staging: wave w covers tile rows [w*32, w*32+32), 4 instr x 8 rows each
    const int lr = lane >> 3;                 // 0..7 local row
    const int lc = (lane & 7) ^ lr;           // swizzled source chunk
    const size_t aRow = (size_t)(m0 + wave * 32 + lr);
    const size_t bRow = (size_t)(n0 + wave * 32 + lr);

    floatx4 acc[4][4];
    #pragma unroll
    for (int i = 0; i < 4; ++i)
        #pragma unroll
        for (int j = 0; j < 4; ++j) acc[i][j] = (floatx4)0.f;

    for (int k0 = 0; k0 < DIM; k0 += 64) {
        #pragma unroll
        for (int q = 0; q < 4; ++q) {
            gld_lds16(A + (aRow + q * 8) * DIM + k0 + lc * 8,
                      &As[(wave * 32 + q * 8) * 64]);
            gld_lds16(Bm + (bRow + q * 8) * DIM + k0 + lc * 8,
                      &Bs[(wave * 32 + q * 8) * 64]);
        }
        __syncthreads();   // drains vmcnt(0) -> staged tile visible

        bf16x8 af[2][4], bv[2][4];
        #pragma unroll
        for (int kb = 0; kb < 2; ++kb) {
            #pragma unroll
            for (int i = 0; i < 4; ++i) {
                const int r = wm + i * 16 + l15;
                const int c = (kb * 4 + quad) ^ (r & 7);
                af[kb][i] = *(const bf16x8*)&As[r * 64 + c * 8];
            }
            #pragma unroll
            for (int j = 0; j < 4; ++j) {
                const int r = wn + j * 16 + l15;
                const int c = (kb * 4 + quad) ^ (r & 7);
                bv[kb][j] = *(const bf16x8*)&Bs[r * 64 + c * 8];
            }
        }
        #pragma unroll
        for (int kb = 0; kb < 2; ++kb)
            #pragma unroll
            for (int i = 0; i < 4; ++i)
                #pragma unroll
                for (int j = 0; j < 4; ++j)
                    acc[i][j] = __builtin_amdgcn_mfma_f32_16x16x32_bf16(
                        af[kb][i], bv[kb][j], acc[i][j], 0, 0, 0);
        __syncthreads();   // protect LDS from next iter's staging
    }

    // epilogue: scores[m] += sum_n tanh(acc + ht[n]) * Va[n]
    // C/D layout: n = lane&15, m = quad*4 + reg   [m89-verified, passed R1]
    const int bb = m0 >> 11;
    float htv[4], vav[4];
    #pragma unroll
    for (int j = 0; j < 4; ++j) {
        const int ng = n0 + wn + j * 16 + l15;
        htv[j] = ht[bb * DIM + ng];
        vav[j] = Va[ng];
    }
    #pragma unroll
    for (int i = 0; i < 4; ++i) {
        #pragma unroll
        for (int r = 0; r < 4; ++r) {
            float s = 0.f;
            #pragma unroll
            for (int j = 0; j < 4; ++j)
                s += tanh_fast(acc[i][j][r] + htv[j]) * vav[j];
            s += __shfl_xor(s, 8);
            s += __shfl_xor(s, 4);
            s += __shfl_xor(s, 2);
            s += __shfl_xor(s, 1);
            if (l15 == 0)
                atomicAdd(&scores[m0 + wm + i * 16 + quad * 4 + r], s);
        }
    }
}

// ---------------------------------------------------------------------------
// fallback fp32-staging GEMM (round-1, used only if ws too small)
// ---------------------------------------------------------------------------
#define LDS_STRIDE 40
__global__ __launch_bounds__(256, 2) void gemm_score_kernel(
    const float* __restrict__ ctx, const float* __restrict__ Wa,
    const float* __restrict__ Va, const float* __restrict__ ht,
    float* __restrict__ scores)
{
    __shared__ unsigned short As[BM * LDS_STRIDE];
    __shared__ unsigned short Bs[BN * LDS_STRIDE];
    const int t = threadIdx.x;
    const int n0 = blockIdx.x * BN;
    const int m0 = blockIdx.y * BM;
    const int lane = t & 63, wave = t >> 6;
    const int l15 = lane & 15, quad = lane >> 4;
    const int wm = (wave >> 1) * 64, wn = (wave & 1) * 64;
    const int srow = t >> 3;
    const int scol = (t & 7) * 4;
    const float* aBase = ctx + (size_t)(m0 + srow) * DIM + scol;
    const float* bBase = Wa + (size_t)(n0 + srow) * (2 * DIM) + DIM + scol;

    floatx4 acc[4][4];
    #pragma unroll
    for (int i = 0; i < 4; ++i)
        #pragma unroll
        for (int j = 0; j < 4; ++j) acc[i][j] = (floatx4)0.f;

    for (int k0 = 0; k0 < DIM; k0 += 32) {
        __syncthreads();
        #pragma unroll
        for (int r = 0; r < 4; ++r) {
            const float4 va = *(const float4*)(aBase + (size_t)(r * 32) * DIM + k0);
            const float4 vb = *(const float4*)(bBase + (size_t)(r * 32) * (2 * DIM) + k0);
            *(uint2*)&As[(srow + r * 32) * LDS_STRIDE + scol] =
                make_uint2(cvt2_bf16_rne(va.x, va.y), cvt2_bf16_rne(va.z, va.w));
            *(uint2*)&Bs[(srow + r * 32) * LDS_STRIDE + scol] =
                make_uint2(cvt2_bf16_rne(vb.x, vb.y), cvt2_bf16_rne(vb.z, vb.w));
        }
        __syncthreads();
        bf16x8 af[4], bfr[4];
        #pragma unroll
        for (int i = 0; i < 4; ++i)
            af[i] = *(const bf16x8*)&As[(wm + i * 16 + l15) * LDS_STRIDE + quad * 8];
        #pragma unroll
        for (int j = 0; j < 4; ++j)
            bfr[j] = *(const bf16x8*)&Bs[(wn + j * 16 + l15) * LDS_STRIDE + quad * 8];
        #pragma unroll
        for (int i = 0; i < 4; ++i)
            #pragma unroll
            for (int j = 0; j < 4; ++j)
                acc[i][j] = __builtin_amdgcn_mfma_f32_16x16x32_bf16(af[i], bfr[j], acc[i][j], 0, 0, 0);
    }
    const int bb = m0 >> 11;
    float htv[4], vav[4];
    #pragma unroll
    for (int j = 0; j < 4; ++j) {
        const int ng = n0 + wn + j * 16 + l15;
        htv[j] = ht[bb * DIM + ng];
        vav[j] = Va[ng];
    }
    #pragma unroll
    for (int i = 0; i < 4; ++i) {
        #pragma unroll
        for (int r = 0; r < 4; ++r) {
            float s = 0.f;
            #pragma unroll
            for (int j = 0; j < 4; ++j)
                s += tanh_fast(acc[i][j][r] + htv[j]) * vav[j];
            s += __shfl_xor(s, 8);
            s += __shfl_xor(s, 4);
            s += __shfl_xor(s, 2);
            s += __shfl_xor(s, 1);
            if (l15 == 0)
                atomicAdd(&scores[m0 + wm + i * 16 + quad * 4 + r], s);
        }
    }
}

// ---------------------------------------------------------------------------
// softmax over L per batch row
// ---------------------------------------------------------------------------
__global__ __launch_bounds__(256) void softmax_kernel(const float* __restrict__ scores,
                                                      float* __restrict__ attn) {
    const int b = blockIdx.x, t = threadIdx.x;
    const float* sc = scores + b * L_SZ;
    float* at = attn + b * L_SZ;
    __shared__ float red[256];
    float m = -1e30f;
    for (int l = t; l < L_SZ; l += 256) m = fmaxf(m, sc[l]);
    red[t] = m; __syncthreads();
    for (int s = 128; s > 0; s >>= 1) { if (t < s) red[t] = fmaxf(red[t], red[t + s]); __syncthreads(); }
    m = red[0]; __syncthreads();
    float sum = 0.f;
    for (int l = t; l < L_SZ; l += 256) sum += __expf(sc[l] - m);
    red[t] = sum; __syncthreads();
    for (int s = 128; s > 0; s >>= 1) { if (t < s) red[t] += red[t + s]; __syncthreads(); }
    const float inv = 1.0f / red[0];
    for (int l = t; l < L_SZ; l += 256) at[l] = __expf(sc[l] - m) * inv;
}

// ---------------------------------------------------------------------------
// weighted from bf16 ctx: block=128 threads, each owns 8 d-columns (16B load)
// ---------------------------------------------------------------------------
__global__ __launch_bounds__(128) void weighted_bf16_kernel(
    const unsigned short* __restrict__ ctxb, const float* __restrict__ attn,
    float* __restrict__ weighted) {
    const int b = blockIdx.x, slice = blockIdx.y, t = threadIdx.x;
    const unsigned short* cb = ctxb + ((size_t)b * L_SZ + (size_t)slice * 128) * DIM + t * 8;
    const float* at = attn + b * L_SZ + slice * 128;
    float acc[8] = {0.f, 0.f, 0.f, 0.f, 0.f, 0.f, 0.f, 0.f};
    for (int l = 0; l < 128; ++l) {
        const float a = at[l];
        const uint4 v = *(const uint4*)(cb + (size_t)l * DIM);
        const unsigned w0 = v.x, w1 = v.y, w2 = v.z, w3 = v.w;
        acc[0] += a * bf2f((unsigned short)(w0 & 0xFFFF));
        acc[1] += a * bf2f((unsigned short)(w0 >> 16));
        acc[2] += a * bf2f((unsigned short)(w1 & 0xFFFF));
        acc[3] += a * bf2f((unsigned short)(w1 >> 16));
        acc[4] += a * bf2f((unsigned short)(w2 & 0xFFFF));
        acc[5] += a * bf2f((unsigned short)(w2 >> 16));
        acc[6] += a * bf2f((unsigned short)(w3 & 0xFFFF));
        acc[7] += a * bf2f((unsigned short)(w3 >> 16));
    }
    float* o = weighted + b * DIM + t * 8;
    #pragma unroll
    for (int e = 0; e < 8; ++e) atomicAdd(o + e, acc[e]);
}

// fallback fp32 weighted
__global__ __launch_bounds__(256) void weighted_kernel(const float* __restrict__ ctx,
                                                       const float* __restrict__ attn,
                                                       float* __restrict__ weighted) {
    const int b = blockIdx.x, slice = blockIdx.y, t = threadIdx.x;
    const float* cb = ctx + ((size_t)b * L_SZ + (size_t)slice * 128) * DIM;
    const float* at = attn + b * L_SZ + slice * 128;
    float4 w = make_float4(0.f, 0.f, 0.f, 0.f);
    for (int l = 0; l < 128; ++l) {
        const float a = at[l];
        const float4 c = *(const float4*)(cb + (size_t)l * DIM + t * 4);
        w.x += a * c.x; w.y += a * c.y; w.z += a * c.z; w.w += a * c.w;
    }
    float* o = weighted + b * DIM + t * 4;
    atomicAdd(o + 0, w.x);
    atomicAdd(o + 1, w.y);
    atomicAdd(o + 2, w.z);
    atomicAdd(o + 3, w.w);
}

extern "C" void kernel_launch(void* const* d_in, const int* in_sizes, int n_in,
                              void* d_out, int out_size, void* d_ws, size_t ws_size,
                              hipStream_t stream) {
    const float* x   = (const float*)d_in[0];   // 32 x 1024
    const float* ctx = (const float*)d_in[1];   // 32 x 2048 x 1024
    const float* Wa  = (const float*)d_in[2];   // 1024 x 2048
    const float* Va  = (const float*)d_in[3];   // 1 x 1024

    float* out      = (float*)d_out;
    float* weighted = out;                      // 32*1024
    float* attn     = out + B_SZ * DIM;         // 32*2048

    float* scores = (float*)d_ws;               // 256 KB
    float* ht     = scores + B_SZ * L_SZ;       // 128 KB

    const size_t base = (size_t)(B_SZ * L_SZ + B_SZ * DIM) * sizeof(float);
    const size_t need = base + (size_t)DIM * DIM * 2            // Wa_s bf16: 2 MB
                      + (size_t)B_SZ * L_SZ * DIM * 2;          // ctx bf16: 128 MB

    hipMemsetAsync(scores, 0, (size_t)B_SZ * L_SZ * sizeof(float), stream);
    hipMemsetAsync(weighted, 0, (size_t)B_SZ * DIM * sizeof(float), stream);

    ht_kernel<<<dim3(B_SZ, 16), 256, 0, stream>>>(x, Wa, ht);

    if (ws_size >= need) {
        unsigned short* WaB  = (unsigned short*)((char*)d_ws + base);
        unsigned short* ctxB = WaB + (size_t)DIM * DIM;
        cvt_wa_kernel<<<512, 256, 0, stream>>>(Wa, WaB);
        cvt_ctx_kernel<<<8192, 256, 0, stream>>>(ctx, ctxB,
                                                 (long)B_SZ * L_SZ * DIM / 8);
        gemm_score_bf16<<<dim3(DIM / BN, (B_SZ * L_SZ) / BM), 256, 0, stream>>>(
            ctxB, WaB, Va, ht, scores);
        softmax_kernel<<<B_SZ, 256, 0, stream>>>(scores, attn);
        weighted_bf16_kernel<<<dim3(B_SZ, 16), 128, 0, stream>>>(ctxB, attn, weighted);
    } else {
        gemm_score_kernel<<<dim3(DIM / BN, (B_SZ * L_SZ) / BM), 256, 0, stream>>>(
            ctx, Wa, Va, ht, scores);
        softmax_kernel<<<B_SZ, 256, 0, stream>>>(scores, attn);
        weighted_kernel<<<dim3(B_SZ, 16), 256, 0, stream>>>(ctx, attn, weighted);
    }
}